// Round 11
// baseline (176.700 us; speedup 1.0000x reference)
//
#include <hip/hip_runtime.h>
#include <hip/hip_bf16.h>

// LocalActivationUnit: score[b,t] = relu([q,k,q-k,q*k]·W0 + b0)·W1 + b1
// R11: algebraic split to kill the per-batch W0 re-read.
//   pre-act[b,t,h] = bias_all[b,h] + k·P1 + (q⊙k)·W0d
//   P1 = W0[128:256]-W0[256:384]  (batch-INDEPENDENT)
//   W0d = W0[384:512]             (batch-INDEPENDENT)
//   bias_all[b] = q[b]·(W0[0:128]+W0[256:384]) + b0   (tiny precompute)
// Evidence: R0/R9/R10 all sit at 5.0-6.0 TB/s of TOTAL load-path bytes
// (keys 105MB + W0 refold 134MB = 240MB); R10 = 240MB/40us = 6.0 TB/s ~=
// the 6.3 TB/s chip load ceiling. The lever is BYTES, not shape/latency.
// This version: prep kernel materializes Wcat[64][264] bf16 (P1||W0d, K=256,
// B-fragment layout) + bias_all; main kernel does 2 batches/block, staging
// Wcat ONCE per block (33KB vs 131KB/batch). A = [k || q⊙k]: k staged via
// R10's NT copy-shaped path; q⊙k fragments derived in-register (k_frag × q).
// Load-path bytes: 240MB -> ~123MB. Predict main ~20-24us, dur 147-155.

#define TB 200
#define EB 128
#define HB 64
#define KROW 136            // kt row stride (bf16): 272 B, proven conflict profile
#define KT_ROWS 112
#define WCOL 264            // wcat row stride (bf16): 528 B, 528%128==16 (same profile)
#define UNITS_B 6400        // float4 units per batch (200*128/4)
#define U_H1 3584           // 112 rows * 32 units

typedef __attribute__((ext_vector_type(8))) short bf16x8;
typedef __attribute__((ext_vector_type(4))) float f32x4;

// ---------------- prep: Wcat + bias_all ----------------
__global__ __launch_bounds__(256, 4)
void prep_kernel(const float* __restrict__ query,
                 const float* __restrict__ W0,
                 const float* __restrict__ b0,
                 unsigned char* __restrict__ ws)
{
    const int bid = blockIdx.x, tid = threadIdx.x;
    __hip_bfloat16* wcat_g = (__hip_bfloat16*)ws;          // [64][264] bf16
    float* bias_g = (float*)(ws + 34048);                  // [1024][64] f32

    if (bid < 64) {
        // bias_all for batches bid*16 .. bid*16+15
        __shared__ float p2s[EB][HB];                      // 32 KB
        const int h = tid & 63, ec = tid >> 6;
        #pragma unroll 4
        for (int i = 0; i < 32; ++i) {
            const int e = ec * 32 + i;
            p2s[e][h] = W0[(size_t)e * HB + h] + W0[(size_t)(2 * EB + e) * HB + h];
        }
        __syncthreads();
        const float b0h = b0[h];
        for (int pass = 0; pass < 4; ++pass) {
            const int b = bid * 16 + (tid >> 6) + pass * 4;
            const float* q = query + (size_t)b * EB;
            float acc = b0h;
            #pragma unroll 8
            for (int e = 0; e < EB; ++e) acc += q[e] * p2s[e][h];
            bias_g[(size_t)b * HB + h] = acc;
        }
    } else {
        // Wcat: kc = (bid-64)*4 + (tid>>6) in [0,256), h = tid&63 (coalesced)
        const int h  = tid & 63;
        const int kc = (bid - 64) * 4 + (tid >> 6);
        float v;
        if (kc < 128) v = W0[(size_t)(EB + kc) * HB + h] - W0[(size_t)(2 * EB + kc) * HB + h];
        else          v = W0[(size_t)(3 * EB + (kc - 128)) * HB + h];
        wcat_g[(size_t)h * WCOL + kc] = __float2bfloat16(v);
        // pad cols 256..263 never read as fragments; left unwritten on purpose
    }
}

// ---------------- main: 2 batches per 512-thread block ----------------
__global__ __launch_bounds__(512, 4)
void lau_main(const float* __restrict__ query,
              const float* __restrict__ keys,
              const float* __restrict__ W1,
              const float* __restrict__ b1,
              const unsigned char* __restrict__ ws,
              float* __restrict__ out)
{
    const int bid  = blockIdx.x, tid = threadIdx.x;
    const int lane = tid & 63, wave = tid >> 6;
    const int ln15 = lane & 15, quad = lane >> 4;

    __shared__ __align__(16) __hip_bfloat16 wcat_s[HB][WCOL];   // 33792 B
    __shared__ __align__(16) __hip_bfloat16 kt[KT_ROWS][KROW];  // 30464 B
    __shared__ float q_s[EB];
    __shared__ float bias_s[HB];
    __shared__ float w1_s[HB];

    const __hip_bfloat16* wcat_g = (const __hip_bfloat16*)ws;
    const float* bias_g = (const float*)(ws + 34048);
    const float b1v = b1[0];

    int b = bid * 2;
    const float* kb = keys + (size_t)b * TB * EB;

    // ---- issue H1(b0) key loads first (NT, longest latency leads queue) ----
    f32x4 g[7];
    #pragma unroll
    for (int j = 0; j < 7; ++j)
        g[j] = __builtin_nontemporal_load((const f32x4*)(kb + (size_t)(tid + j * 512) * 4));

    // ---- stage wcat (flat uint4 copy) + q/bias/w1 for b0 ----
    {
        const uint4* src = (const uint4*)wcat_g;
        uint4* dst = (uint4*)&wcat_s[0][0];
        #pragma unroll
        for (int j = 0; j < 4; ++j) dst[tid + j * 512] = src[tid + j * 512];
        if (tid < 64) dst[2048 + tid] = src[2048 + tid];     // 2112 total
        if (tid < EB) q_s[tid] = query[(size_t)b * EB + tid];
        if (tid < HB) { bias_s[tid] = bias_g[(size_t)b * HB + tid]; w1_s[tid] = W1[tid]; }
    }
    __syncthreads();

    float w1q[4];
    #pragma unroll
    for (int nt = 0; nt < 4; ++nt) w1q[nt] = w1_s[nt * 16 + ln15];

    float biasq[4];

    // per-tile compute: K=256 MFMA (k from LDS, q⊙k derived in-register)
    auto do_tile = [&](int mt, int lrow) {
        bf16x8 ak[4];
        #pragma unroll
        for (int ks = 0; ks < 4; ++ks)
            ak[ks] = *(const bf16x8*)&kt[lrow][quad * 8 + ks * 32];
        f32x4 acc[4] = {{0,0,0,0},{0,0,0,0},{0,0,0,0},{0,0,0,0}};
        #pragma unroll
        for (int ks = 0; ks < 4; ++ks) {
            #pragma unroll
            for (int nt = 0; nt < 4; ++nt) {
                const bf16x8 bf = *(const bf16x8*)&wcat_s[nt * 16 + ln15][quad * 8 + ks * 32];
                acc[nt] = __builtin_amdgcn_mfma_f32_16x16x32_bf16(ak[ks], bf, acc[nt], 0, 0, 0);
            }
        }
        #pragma unroll
        for (int ks = 0; ks < 4; ++ks) {
            union { bf16x8 v; __hip_bfloat162 h2[4]; } kk, qq;
            kk.v = ak[ks];
            #pragma unroll
            for (int j = 0; j < 4; ++j) {
                const float2 kf = __bfloat1622float2(kk.h2[j]);
                const int e = quad * 8 + ks * 32 + 2 * j;
                qq.h2[j] = __float22bfloat162_rn(make_float2(kf.x * q_s[e], kf.y * q_s[e + 1]));
            }
            #pragma unroll
            for (int nt = 0; nt < 4; ++nt) {
                const bf16x8 bf = *(const bf16x8*)&wcat_s[nt * 16 + ln15][128 + quad * 8 + ks * 32];
                acc[nt] = __builtin_amdgcn_mfma_f32_16x16x32_bf16(qq.v, bf, acc[nt], 0, 0, 0);
            }
        }
        // epilogue: relu+bias, dot W1, reduce over n (16 lanes). C: n=ln15, m=quad*4+r
        float part[4];
        #pragma unroll
        for (int r = 0; r < 4; ++r) {
            float s = 0.f;
            #pragma unroll
            for (int nt = 0; nt < 4; ++nt) {
                float hv = acc[nt][r] + biasq[nt];
                hv = hv > 0.f ? hv : 0.f;
                s += hv * w1q[nt];
            }
            part[r] = s;
        }
        #pragma unroll
        for (int m = 1; m < 16; m <<= 1) {
            #pragma unroll
            for (int r = 0; r < 4; ++r) part[r] += __shfl_xor(part[r], m, 64);
        }
        if (ln15 == 0) {
            #pragma unroll
            for (int r = 0; r < 4; ++r) {
                const int mg = mt * 16 + quad * 4 + r;
                if (mg < TB) out[(size_t)b * TB + mg] = part[r] + b1v;
            }
        }
    };

    for (int bt = 0; bt < 2; ++bt) {
        // ---- write H1 (rows 0..111) ----
        #pragma unroll
        for (int j = 0; j < 7; ++j) {
            const int u = tid + j * 512;
            const int row = u >> 5, col4 = (u & 31) * 4;
            union { uint2 w; __hip_bfloat162 h2[2]; } pk;
            pk.h2[0] = __float22bfloat162_rn(make_float2(g[j][0], g[j][1]));
            pk.h2[1] = __float22bfloat162_rn(make_float2(g[j][2], g[j][3]));
            *(uint2*)&kt[row][col4] = pk.w;
        }
        // ---- issue H2 (rows 112..207, clamped at batch end) ----
        #pragma unroll
        for (int j = 0; j < 6; ++j) {
            int gu = U_H1 + tid + j * 512;
            gu = gu < UNITS_B ? gu : UNITS_B - 1;
            g[j] = __builtin_nontemporal_load((const f32x4*)(kb + (size_t)gu * 4));
        }
        __syncthreads();   // kt-H1 + (bt==1: b1's q_s/bias_s) visible

        #pragma unroll
        for (int nt = 0; nt < 4; ++nt) biasq[nt] = bias_s[nt * 16 + ln15];

        // ---- MFMA H1: tiles 0..6 ----
        if (wave < 7) do_tile(wave, wave * 16 + ln15);
        __syncthreads();   // kt consumed

        // ---- write H2 ----
        #pragma unroll
        for (int j = 0; j < 6; ++j) {
            const int u = tid + j * 512;
            const int row = u >> 5, col4 = (u & 31) * 4;
            union { uint2 w; __hip_bfloat162 h2[2]; } pk;
            pk.h2[0] = __float22bfloat162_rn(make_float2(g[j][0], g[j][1]));
            pk.h2[1] = __float22bfloat162_rn(make_float2(g[j][2], g[j][3]));
            *(uint2*)&kt[row][col4] = pk.w;
        }
        // ---- issue next batch's H1 while H2 computes ----
        if (bt == 0) {
            const float* kb1 = keys + (size_t)(b + 1) * TB * EB;
            #pragma unroll
            for (int j = 0; j < 7; ++j)
                g[j] = __builtin_nontemporal_load((const f32x4*)(kb1 + (size_t)(tid + j * 512) * 4));
        }
        __syncthreads();   // kt-H2 ready (q_s still batch b's)

        // ---- MFMA H2: tiles 7..12 (local rows 0..95) ----
        if (wave < 6) do_tile(7 + wave, (7 + wave) * 16 - 112 + ln15);
        __syncthreads();   // kt + q_s consumed

        if (bt == 0) {
            b += 1;
            kb = keys + (size_t)b * TB * EB;
            if (tid < EB) q_s[tid] = query[(size_t)b * EB + tid];
            if (tid < HB) bias_s[tid] = bias_g[(size_t)b * HB + tid];
            // visibility guaranteed by next iteration's first __syncthreads
        }
    }
}

extern "C" void kernel_launch(void* const* d_in, const int* in_sizes, int n_in,
                              void* d_out, int out_size, void* d_ws, size_t ws_size,
                              hipStream_t stream) {
    const float* query = (const float*)d_in[0];
    const float* keys  = (const float*)d_in[1];
    const float* W0    = (const float*)d_in[2];
    const float* b0    = (const float*)d_in[3];
    const float* W1    = (const float*)d_in[4];
    const float* b1    = (const float*)d_in[5];
    float* out = (float*)d_out;
    unsigned char* ws = (unsigned char*)d_ws;

    prep_kernel<<<128, 256, 0, stream>>>(query, W0, b0, ws);
    lau_main<<<512, 512, 0, stream>>>(query, keys, W1, b1, ws, out);
}

// Round 12
// 170.464 us; speedup vs baseline: 1.0366x; 1.0366x over previous
//
#include <hip/hip_runtime.h>
#include <hip/hip_bf16.h>

// LocalActivationUnit: score[b,t] = relu([q,k,q-k,q*k]·W0 + b0)·W1 + b1
// Folded: Wb[e][h] = W0[128+e][h] - W0[256+e][h] + q[e]*W0[384+e][h]
//         bias[h]  = sum_e q[e]*(W0[e][h] + W0[256+e][h]) + b0[h]
//         h = relu(k·Wb + bias);  score = h·W1 + b1
//
// R12: R10's exact score structure (K=128, NT copy-shaped key staging, one
// barrier) with the fold AMORTIZED into a multi-batch prep kernel.
// Evidence: R10 = 40us at 239 MB load-path (6.0 TB/s ~ ceiling); R11 halved
// bytes but doubled MFMA (K=256) + VALU + barriers -> 54.7us. So: cut W0
// bytes while keeping K=128 and R10's schedule untouched.
//  - prep: 256 blocks x 512 thr; W0 slice held in REGISTERS (64 f/thread,
//    one coalesced 256-B row read per wave-instr), loops 4 batches ->
//    W0 traffic 134 MB -> 33.5 MB. Writes Wb bf16 [64][128]/batch (16.8 MB)
//    + bias_all f32 [1024][64].
//  - score: R10 minus fold. wbf hoisted from ws via 16x16-B global reads
//    (L2/L3-resident); keys NT-staged to kt LDS; single __syncthreads.
// Load-path: 239 -> ~172 MB, zero extra compute. Predict dur 150-158.
// Falsification: >=162 -> byte model dead, declare ROOFLINE.

#define TB 200
#define EB 128
#define HB 64
#define KROW 136            // kt row stride bf16: 272 B (proven b128 profile)
#define KROWS 208           // 13 tiles * 16 rows (200 valid, 8 junk, masked)
#define WB_BYTES (HB * EB * 2)              // 16384 B per batch
#define BIAS_OFF (1024 * WB_BYTES)          // 16.78 MB, then bias f32[1024][64]

typedef __attribute__((ext_vector_type(8))) short bf16x8;
typedef __attribute__((ext_vector_type(4))) float f32x4;

// ---------------- prep: Wb + bias for 4 batches per block ----------------
__global__ __launch_bounds__(512, 2)
void prep_kernel(const float* __restrict__ query,
                 const float* __restrict__ W0,
                 const float* __restrict__ b0,
                 unsigned char* __restrict__ ws)
{
    const int bid = blockIdx.x, tid = threadIdx.x;
    const int h     = tid & 63;        // lane-consecutive -> 256-B row loads
    const int chunk = tid >> 6;        // 0..7, 16 e's each

    __shared__ float q_s[4][EB];
    __shared__ float red_s[512];

    // stage 4 q vectors
    for (int j = tid; j < 4 * EB; j += 512) {
        const int bb = bid * 4 + (j >> 7);
        q_s[j >> 7][j & 127] = query[(size_t)bb * EB + (j & 127)];
    }

    // W0 slice -> registers (coalesced: one 256-B row per wave-instr)
    float w0a[16], w0b[16], w0c[16], w0d[16];
    #pragma unroll
    for (int i = 0; i < 16; ++i) {
        const int e = chunk * 16 + i;
        w0a[i] = W0[(size_t)e            * HB + h];
        w0b[i] = W0[(size_t)(EB + e)     * HB + h];
        w0c[i] = W0[(size_t)(2 * EB + e) * HB + h];
        w0d[i] = W0[(size_t)(3 * EB + e) * HB + h];
    }
    __syncthreads();

    const float b0h = b0[h];
    for (int bt = 0; bt < 4; ++bt) {
        const int b = bid * 4 + bt;
        __hip_bfloat16* wb_g = (__hip_bfloat16*)(ws + (size_t)b * WB_BYTES);
        float biasp = 0.f;
        __hip_bfloat16 wbv[16];
        #pragma unroll
        for (int i = 0; i < 16; ++i) {
            const int e = chunk * 16 + i;
            const float qe = q_s[bt][e];
            wbv[i] = __float2bfloat16(w0b[i] - w0c[i] + qe * w0d[i]);
            biasp += qe * (w0a[i] + w0c[i]);
        }
        // 32-B store per thread: wb_g[h][chunk*16 .. +15]
        *(uint4*)&wb_g[(size_t)h * EB + chunk * 16]     = *(uint4*)&wbv[0];
        *(uint4*)&wb_g[(size_t)h * EB + chunk * 16 + 8] = *(uint4*)&wbv[8];

        red_s[tid] = biasp;
        __syncthreads();
        if (tid < HB) {
            float s = b0h;
            #pragma unroll
            for (int j = 0; j < 8; ++j) s += red_s[tid + 64 * j];
            ((float*)(ws + BIAS_OFF))[(size_t)b * HB + tid] = s;
        }
        __syncthreads();
    }
}

// ---------------- score: R10 structure minus the fold ----------------
__global__ __launch_bounds__(512, 4)
void score_kernel(const float* __restrict__ keys,
                  const float* __restrict__ W1,
                  const float* __restrict__ b1,
                  const unsigned char* __restrict__ ws,
                  float* __restrict__ out)
{
    const int b    = blockIdx.x;
    const int tid  = threadIdx.x;
    const int lane = tid & 63;
    const int wave = tid >> 6;          // 0..7
    const int ln15 = lane & 15;
    const int quad = lane >> 4;

    __shared__ __align__(16) __hip_bfloat16 kt[KROWS][KROW];   // 56576 B

    const float* kb = keys + (size_t)b * TB * EB;

    // ---- issue half-1 of the key stream (NT, longest latency first) ----
    f32x4 g[7];
    #pragma unroll
    for (int j = 0; j < 7; ++j) {
        const int u = tid + j * 512;
        if (u < 3200) g[j] = __builtin_nontemporal_load((const f32x4*)(kb + (size_t)u * 4));
    }

    // ---- hoist B-fragments from ws (L2/L3) + bias/w1 while keys fly ----
    const __hip_bfloat16* wb_g = (const __hip_bfloat16*)(ws + (size_t)b * WB_BYTES);
    bf16x8 wbf[4][4];
    #pragma unroll
    for (int nt = 0; nt < 4; ++nt)
        #pragma unroll
        for (int ks = 0; ks < 4; ++ks)
            wbf[nt][ks] = *(const bf16x8*)&wb_g[(size_t)(nt * 16 + ln15) * EB + quad * 8 + ks * 32];
    float w1q[4], biasq[4];
    #pragma unroll
    for (int nt = 0; nt < 4; ++nt) {
        w1q[nt]   = W1[nt * 16 + ln15];
        biasq[nt] = ((const float*)(ws + BIAS_OFF))[(size_t)b * HB + nt * 16 + ln15];
    }

    // ---- write half-1 (data-dep waits); issue half-2; write half-2 ----
    #pragma unroll
    for (int j = 0; j < 7; ++j) {
        const int u = tid + j * 512;
        if (u < 3200) {
            const int row = u >> 5, col4 = (u & 31) * 4;
            union { uint2 w; __hip_bfloat162 h2[2]; } pk;
            pk.h2[0] = __float22bfloat162_rn(make_float2(g[j][0], g[j][1]));
            pk.h2[1] = __float22bfloat162_rn(make_float2(g[j][2], g[j][3]));
            *(uint2*)&kt[row][col4] = pk.w;
        }
    }
    #pragma unroll
    for (int j = 0; j < 7; ++j) {
        const int u = 3200 + tid + j * 512;
        if (u < 6400) g[j] = __builtin_nontemporal_load((const f32x4*)(kb + (size_t)u * 4));
    }
    #pragma unroll
    for (int j = 0; j < 7; ++j) {
        const int u = 3200 + tid + j * 512;
        if (u < 6400) {
            const int row = u >> 5, col4 = (u & 31) * 4;
            union { uint2 w; __hip_bfloat162 h2[2]; } pk;
            pk.h2[0] = __float22bfloat162_rn(make_float2(g[j][0], g[j][1]));
            pk.h2[1] = __float22bfloat162_rn(make_float2(g[j][2], g[j][3]));
            *(uint2*)&kt[row][col4] = pk.w;
        }
    }
    __syncthreads();   // the only barrier

    // ---- MFMA tiles from LDS (rows 200..207 junk, outputs masked) ----
    const float b1v = b1[0];
    for (int mt = wave; mt < 13; mt += 8) {
        bf16x8 af[4];
        #pragma unroll
        for (int ks = 0; ks < 4; ++ks)
            af[ks] = *(const bf16x8*)&kt[mt * 16 + ln15][quad * 8 + ks * 32];

        f32x4 acc[4] = {{0,0,0,0},{0,0,0,0},{0,0,0,0},{0,0,0,0}};
        #pragma unroll
        for (int ks = 0; ks < 4; ++ks)
            #pragma unroll
            for (int nt = 0; nt < 4; ++nt)
                acc[nt] = __builtin_amdgcn_mfma_f32_16x16x32_bf16(af[ks], wbf[nt][ks], acc[nt], 0, 0, 0);

        // ---- epilogue: relu+bias, dot W1, reduce over n (16 lanes) ----
        // C layout: n = ln15, m(in-tile) = quad*4 + r
        float part[4];
        #pragma unroll
        for (int r = 0; r < 4; ++r) {
            float s = 0.f;
            #pragma unroll
            for (int nt = 0; nt < 4; ++nt) {
                float hv = acc[nt][r] + biasq[nt];
                hv = hv > 0.f ? hv : 0.f;
                s += hv * w1q[nt];
            }
            part[r] = s;
        }
        #pragma unroll
        for (int m = 1; m < 16; m <<= 1) {
            #pragma unroll
            for (int r = 0; r < 4; ++r)
                part[r] += __shfl_xor(part[r], m, 64);
        }
        if (ln15 == 0) {
            #pragma unroll
            for (int r = 0; r < 4; ++r) {
                const int mg = mt * 16 + quad * 4 + r;
                if (mg < TB) out[(size_t)b * TB + mg] = part[r] + b1v;
            }
        }
    }
}

extern "C" void kernel_launch(void* const* d_in, const int* in_sizes, int n_in,
                              void* d_out, int out_size, void* d_ws, size_t ws_size,
                              hipStream_t stream) {
    const float* query = (const float*)d_in[0];
    const float* keys  = (const float*)d_in[1];
    const float* W0    = (const float*)d_in[2];
    const float* b0    = (const float*)d_in[3];
    const float* W1    = (const float*)d_in[4];
    const float* b1    = (const float*)d_in[5];
    float* out = (float*)d_out;
    unsigned char* ws = (unsigned char*)d_ws;

    prep_kernel<<<256, 512, 0, stream>>>(query, W0, b0, ws);
    score_kernel<<<1024, 512, 0, stream>>>(keys, W1, b1, ws, out);
}

// Round 13
// 162.785 us; speedup vs baseline: 1.0855x; 1.0472x over previous
//
#include <hip/hip_runtime.h>
#include <hip/hip_bf16.h>

// LocalActivationUnit: score[b,t] = relu([q,k,q-k,q*k]·W0 + b0)·W1 + b1
// Folded: Wb[e][h] = W0[128+e][h] - W0[256+e][h] + q[e]*W0[384+e][h]
//         bias[h]  = sum_e q[e]*(W0[e][h] + W0[256+e][h]) + b0[h]
//         h = relu(k·Wb + bias);  score = h·W1 + b1
//
// R13: single-sweep max-MLP key stream. Evidence chain:
//  - R12 (score == R10 minus fold) ran NO faster than R10 -> the fold is
//    latency-hidden and W0 is L2-resident; only the 105 MB key stream pays.
//  - All 7 structures cap at 2.6 TB/s key-read; R7 (2x blocks, ~256
//    outstanding wave-loads/CU) hit 2.85 TB/s real HBM -> outstanding-bytes
//    correlates with rate. m13 copy bench implies ~3.1 TB/s read ceiling.
//  - This probe: R10 monolithic structure, but ALL 13 float4 loads issued
//    in ONE sweep (no mid-stream barrier, NT), ds_writes drain staggered via
//    counted vmcnt. wbf register-hoist dropped (frees 64 VGPR for the 52-reg
//    payload); B-frags read per-tile from LDS wbt (R0's proven pattern).
//    Outstanding/CU ~112 -> ~208. Everything else byte-identical to R10.
// Predict: dur 156-160 if rate follows concurrency; >=162 -> ROOFLINE.

#define TB 200
#define EB 128
#define HB 64
#define KROW 136            // bf16 row stride: 272 B (proven b128 conflict profile)
#define KROWS 208           // 13 tiles * 16 rows (200 valid, 8 junk, masked)
#define UNITS_B 6400        // float4 units per batch (200*128/4)

typedef __attribute__((ext_vector_type(8))) short bf16x8;
typedef __attribute__((ext_vector_type(4))) float f32x4;

__global__ __launch_bounds__(512, 4)
void lau_kernel(const float* __restrict__ query,
                const float* __restrict__ keys,
                const float* __restrict__ W0,
                const float* __restrict__ b0,
                const float* __restrict__ W1,
                const float* __restrict__ b1,
                float* __restrict__ out)
{
    const int b    = blockIdx.x;
    const int tid  = threadIdx.x;
    const int lane = tid & 63;
    const int wave = tid >> 6;          // 0..7
    const int ln15 = lane & 15;
    const int quad = lane >> 4;

    __shared__ float q_s[EB];
    __shared__ float red_s[512];
    __shared__ float bias_s[HB];
    __shared__ float w1_s[HB];
    __shared__ __align__(16) __hip_bfloat16 wbt[HB][KROW];     // 17408 B, persistent
    __shared__ __align__(16) __hip_bfloat16 kt[KROWS][KROW];   // 56576 B
    // total ~75.3 KB -> 2 blocks/CU (16 waves/CU), same occupancy as R10

    const float* kb = keys + (size_t)b * TB * EB;

    if (tid < EB) q_s[tid] = query[(size_t)b * EB + tid];
    __syncthreads();

    // ---- per-batch weight fold + bias partials (proven R9/R10 form) ----
    {
        const int h     = tid & 63;
        const int chunk = tid >> 6;       // 0..7, each covers 16 e's
        float biasp = 0.f;
        #pragma unroll 8
        for (int i = 0; i < 16; ++i) {
            const int e = chunk * 16 + i;
            const float qe  = q_s[e];
            const float w0a = W0[(size_t)e            * HB + h];
            const float w0b = W0[(size_t)(EB + e)     * HB + h];
            const float w0c = W0[(size_t)(2 * EB + e) * HB + h];
            const float w0d = W0[(size_t)(3 * EB + e) * HB + h];
            wbt[h][e] = __float2bfloat16(w0b - w0c + qe * w0d);
            biasp += qe * (w0a + w0c);
        }
        red_s[tid] = biasp;
    }
    __syncthreads();
    if (tid < HB) {
        float s = b0[tid];
        #pragma unroll
        for (int j = 0; j < 8; ++j) s += red_s[tid + 64 * j];
        bias_s[tid] = s;
        w1_s[tid]   = W1[tid];
    }

    // ---- THE PROBE: issue the ENTIRE key stream in one sweep (13 NT loads
    // per thread, ~208 outstanding wave-loads/CU), no intervening barrier ----
    f32x4 g[13];
    #pragma unroll
    for (int j = 0; j < 13; ++j) {
        int u = tid + j * 512;
        u = u < UNITS_B ? u : UNITS_B - 1;      // clamp: valid mem, rows 200+ junk
        g[j] = __builtin_nontemporal_load((const f32x4*)(kb + (size_t)u * 4));
    }
    // writes drain staggered: write j waits (counted vmcnt) only for load j
    #pragma unroll
    for (int j = 0; j < 13; ++j) {
        int u = tid + j * 512;
        u = u < UNITS_B ? u : UNITS_B - 1;
        const int row = u >> 5, col4 = (u & 31) * 4;
        union { uint2 w; __hip_bfloat162 h2[2]; } pk;
        pk.h2[0] = __float22bfloat162_rn(make_float2(g[j][0], g[j][1]));
        pk.h2[1] = __float22bfloat162_rn(make_float2(g[j][2], g[j][3]));
        *(uint2*)&kt[row][col4] = pk.w;         // clamped dup-writes: same value
    }
    __syncthreads();   // kt + bias_s/w1_s visible

    // ---- MFMA tiles from LDS; B-frags from wbt (R0 pattern, 64 VGPRs freed) ----
    const __hip_bfloat16* wb_base = &wbt[ln15][quad * 8];
    float w1q[4], biasq[4];
    #pragma unroll
    for (int nt = 0; nt < 4; ++nt) {
        w1q[nt]   = w1_s[nt * 16 + ln15];
        biasq[nt] = bias_s[nt * 16 + ln15];
    }
    const float b1v = b1[0];

    for (int mt = wave; mt < 13; mt += 8) {
        bf16x8 af[4];
        #pragma unroll
        for (int ks = 0; ks < 4; ++ks)
            af[ks] = *(const bf16x8*)&kt[mt * 16 + ln15][quad * 8 + ks * 32];

        f32x4 acc[4] = {{0,0,0,0},{0,0,0,0},{0,0,0,0},{0,0,0,0}};
        #pragma unroll
        for (int ks = 0; ks < 4; ++ks)
            #pragma unroll
            for (int nt = 0; nt < 4; ++nt) {
                const bf16x8 bf = *(const bf16x8*)(wb_base + nt * 16 * KROW + ks * 32);
                acc[nt] = __builtin_amdgcn_mfma_f32_16x16x32_bf16(af[ks], bf, acc[nt], 0, 0, 0);
            }

        // ---- epilogue: relu+bias, dot W1, reduce over n (16 lanes) ----
        // C layout: n = ln15, m(in-tile) = quad*4 + r
        float part[4];
        #pragma unroll
        for (int r = 0; r < 4; ++r) {
            float s = 0.f;
            #pragma unroll
            for (int nt = 0; nt < 4; ++nt) {
                float hv = acc[nt][r] + biasq[nt];
                hv = hv > 0.f ? hv : 0.f;
                s += hv * w1q[nt];
            }
            part[r] = s;
        }
        #pragma unroll
        for (int m = 1; m < 16; m <<= 1) {
            #pragma unroll
            for (int r = 0; r < 4; ++r)
                part[r] += __shfl_xor(part[r], m, 64);
        }
        if (ln15 == 0) {
            #pragma unroll
            for (int r = 0; r < 4; ++r) {
                const int mg = mt * 16 + quad * 4 + r;
                if (mg < TB) out[(size_t)b * TB + mg] = part[r] + b1v;
            }
        }
    }
}

extern "C" void kernel_launch(void* const* d_in, const int* in_sizes, int n_in,
                              void* d_out, int out_size, void* d_ws, size_t ws_size,
                              hipStream_t stream) {
    const float* query = (const float*)d_in[0];
    const float* keys  = (const float*)d_in[1];
    const float* W0    = (const float*)d_in[2];
    const float* b0    = (const float*)d_in[3];
    const float* W1    = (const float*)d_in[4];
    const float* b1    = (const float*)d_in[5];
    float* out = (float*)d_out;

    lau_kernel<<<1024, 512, 0, stream>>>(query, keys, W0, b0, W1, b1, out);
}